// Round 3
// baseline (1022.536 us; speedup 1.0000x reference)
//
#include <hip/hip_runtime.h>

// Conv1dFFTInt8: B=16, CIN=128, COUT=128, L=4096, out_size==1.
// Identity: ifft(sum_l X[l]W[l])[0] = sum_n x[n] * w[(L-n) mod L]  (real inputs)
// => out[b,o] = bias[o] + sum_i sum_m w[o,i,m] * x[b,i,(L-m)&(L-1)]
// HBM-bound skinny dot: weight 256MB streamed exactly once; x 32MB L2/L3-resident.
//
// R3: zero LDS, zero barriers. Lane l owns k-slice {m0+4l..+3}; it loads both
// the weight float4 and the (reversed, contiguous) x float4 itself. Waves are
// fully decoupled -> no vmcnt(0) drains except compiler's precise per-use waits.

constexpr int LEN   = 4096;
constexpr int CIN_  = 128;
constexpr int COUT_ = 128;
constexpr int BATCH = 16;

__global__ void init_out_kernel(const float* __restrict__ bias, float* __restrict__ out) {
    int t = blockIdx.x * 256 + threadIdx.x;
    if (t < BATCH * COUT_) out[t] = bias[t & (COUT_ - 1)];
}

// Grid 1024 = ot(8) x ci(128). Block 256 thr = 4 waves; wave owns 4 cout rows,
// acc[16][4] fp32 in VGPRs. Each block covers one input channel (k = ci*4096+m,
// 16 iters of 256). Same-ci blocks differ by ot (stride 128 = 0 mod 8) -> same
// XCD -> shared L2 for the x channel slice.
__global__ __launch_bounds__(256, 3)
void conv_dot_kernel(const float* __restrict__ x, const float* __restrict__ w,
                     float* __restrict__ out) {
    const int tid   = threadIdx.x;
    const int lane  = tid & 63;
    const int wv    = tid >> 6;
    const int bk    = blockIdx.x;     // 0..1023
    const int ot    = bk >> 7;        // 0..7
    const int ci    = bk & 127;       // input channel
    const int obase = ot * 16 + wv * 4;

    const float* xci = x + (ci << 12);
    const float* wrowp[4];
#pragma unroll
    for (int j = 0; j < 4; ++j)
        wrowp[j] = w + (((obase + j) * CIN_ + ci) << 12);

    float acc[BATCH][4];
#pragma unroll
    for (int b = 0; b < BATCH; ++b)
#pragma unroll
        for (int j = 0; j < 4; ++j) acc[b][j] = 0.f;

    float4 wcur[4], wnxt[4];
#pragma unroll
    for (int j = 0; j < 4; ++j)
        wcur[j] = *(const float4*)(wrowp[j] + (lane << 2));

    for (int it = 0; it < 16; ++it) {
        const int m0 = it << 8;
        if (it < 15) {   // cross-iter weight prefetch (the HBM stream)
            const int offn = ((it + 1) << 8) + (lane << 2);
#pragma unroll
            for (int j = 0; j < 4; ++j)
                wnxt[j] = *(const float4*)(wrowp[j] + offn);
        }
        // x: lane l needs k = m0+4l..+3 -> n = (4096-k)&4095, contiguous float4
        // at A = 4093-m0-4l with components REVERSED vs k. Only it==0,lane==0
        // wraps (k=0 -> n=0): special-cased below.
        const int  A     = 4093 - m0 - (lane << 2);
        const bool wrap0 = (it == 0) && (lane == 0);

        float4 xg[4], xn[4];
#pragma unroll
        for (int u = 0; u < 4; ++u) {
            const float* xb = xci + (u << 19);   // b * CIN*LEN
            if (wrap0) { xg[u].x = xb[4093]; xg[u].y = xb[4094]; xg[u].z = xb[4095]; xg[u].w = xb[0]; }
            else        xg[u] = *(const float4*)(xb + A);
        }
#pragma unroll
        for (int bg = 0; bg < 4; ++bg) {
            if (bg < 3) {   // pipeline next batch group's x loads over the FMAs
#pragma unroll
                for (int u = 0; u < 4; ++u) {
                    const float* xb = xci + ((bg * 4 + 4 + u) << 19);
                    if (wrap0) { xn[u].x = xb[4093]; xn[u].y = xb[4094]; xn[u].z = xb[4095]; xn[u].w = xb[0]; }
                    else        xn[u] = *(const float4*)(xb + A);
                }
            }
#pragma unroll
            for (int u = 0; u < 4; ++u) {
                const int b = bg * 4 + u;
#pragma unroll
                for (int j = 0; j < 4; ++j) {
                    // reversed pairing: xv.w<->k=m0+4l (wr.x), etc.
                    acc[b][j] += xg[u].w * wcur[j].x;
                    acc[b][j] += xg[u].z * wcur[j].y;
                    acc[b][j] += xg[u].y * wcur[j].z;
                    acc[b][j] += xg[u].x * wcur[j].w;
                }
            }
            if (bg < 3) {
#pragma unroll
                for (int u = 0; u < 4; ++u) xg[u] = xn[u];
            }
        }
        if (it < 15) {
#pragma unroll
            for (int j = 0; j < 4; ++j) wcur[j] = wnxt[j];
        }
    }

    // epilogue: per-wave shuffle reduction over 64 lanes, one atomic per (b,o)
#pragma unroll
    for (int b = 0; b < BATCH; ++b) {
#pragma unroll
        for (int j = 0; j < 4; ++j) {
            float v = acc[b][j];
            v += __shfl_down(v, 32, 64);
            v += __shfl_down(v, 16, 64);
            v += __shfl_down(v, 8, 64);
            v += __shfl_down(v, 4, 64);
            v += __shfl_down(v, 2, 64);
            v += __shfl_down(v, 1, 64);
            if (lane == 0) atomicAdd(out + b * COUT_ + obase + j, v);
        }
    }
}

extern "C" void kernel_launch(void* const* d_in, const int* in_sizes, int n_in,
                              void* d_out, int out_size, void* d_ws, size_t ws_size,
                              hipStream_t stream) {
    const float* x    = (const float*)d_in[0];   // [16,128,4096]
    const float* wgt  = (const float*)d_in[1];   // [128,128,4096]
    const float* bias = (const float*)d_in[2];   // [128]
    float* out = (float*)d_out;                  // [16,128,1]
    (void)in_sizes; (void)n_in; (void)d_ws; (void)ws_size; (void)out_size;

    init_out_kernel<<<8, 256, 0, stream>>>(bias, out);
    conv_dot_kernel<<<1024, 256, 0, stream>>>(x, wgt, out);
}

// Round 4
// 563.371 us; speedup vs baseline: 1.8150x; 1.8150x over previous
//
#include <hip/hip_runtime.h>

// Conv1dFFTInt8: B=16, CIN=128, COUT=128, L=4096, out_size==1.
// Identity: ifft(sum_l X[l]W[l])[0] = sum_n x[n] * w[(L-n) mod L]  (real inputs)
// => out[b,o] = bias[o] + sum_i sum_m w[o,i,m] * x[b,i,(L-m)&(L-1)]
// HBM-bound skinny dot: weight 256MB streamed exactly once; x 32MB L2/L3-resident.
//
// R4 = R3 structure (zero LDS, zero barriers, decoupled waves) with the R2/R3
// spill bug fixed: __launch_bounds__(256,2). (256,3) capped VGPRs at ~168 while
// the kernel needs ~150 *plus* allocator slack -> acc[16][4] spilled to scratch
// (VGPR_Count=84, WRITE_SIZE ~= 262144 thr * 16 it * 64 acc * 4B = 1.07 GB,
// VALUBusy 4.5%). Registers beat occupancy here: 8 decoupled waves/CU with
// 2-deep load pipelining suffice to stream weight at HBM rate (VALU duty need
// is only ~33% at the 41us HBM floor).

constexpr int LEN   = 4096;
constexpr int CIN_  = 128;
constexpr int COUT_ = 128;
constexpr int BATCH = 16;

__global__ void init_out_kernel(const float* __restrict__ bias, float* __restrict__ out) {
    int t = blockIdx.x * 256 + threadIdx.x;
    if (t < BATCH * COUT_) out[t] = bias[t & (COUT_ - 1)];
}

// Grid 1024 = ot(8) x ci(128). Block 256 thr = 4 waves; wave owns 4 cout rows,
// acc[16][4] fp32 in VGPRs. Each block covers one input channel (k = ci*4096+m,
// 16 iters of 256 k-elems/lane-quad). Same-ci blocks differ by ot (stride 128
// = 0 mod 8) -> same XCD -> shared L2 for that x channel slice; the block's 4
// waves read identical x addresses -> L1 hits for 3 of 4.
__global__ __launch_bounds__(256, 2)   // 2 waves/EU -> 256-VGPR budget, NO SPILL
void conv_dot_kernel(const float* __restrict__ x, const float* __restrict__ w,
                     float* __restrict__ out) {
    const int tid   = threadIdx.x;
    const int lane  = tid & 63;
    const int wv    = tid >> 6;
    const int bk    = blockIdx.x;     // 0..1023
    const int ot    = bk >> 7;        // 0..7
    const int ci    = bk & 127;       // input channel
    const int obase = ot * 16 + wv * 4;

    const float* xci = x + (ci << 12);
    const float* wrowp[4];
#pragma unroll
    for (int j = 0; j < 4; ++j)
        wrowp[j] = w + (((obase + j) * CIN_ + ci) << 12);

    float acc[BATCH][4];
#pragma unroll
    for (int b = 0; b < BATCH; ++b)
#pragma unroll
        for (int j = 0; j < 4; ++j) acc[b][j] = 0.f;

    float4 wcur[4], wnxt[4];
#pragma unroll
    for (int j = 0; j < 4; ++j)
        wcur[j] = *(const float4*)(wrowp[j] + (lane << 2));

    for (int it = 0; it < 16; ++it) {
        const int m0 = it << 8;
        if (it < 15) {   // cross-iter weight prefetch (the HBM stream, aligned)
            const int offn = ((it + 1) << 8) + (lane << 2);
#pragma unroll
            for (int j = 0; j < 4; ++j)
                wnxt[j] = *(const float4*)(wrowp[j] + offn);
        }
        // x: lane l needs k = m0+4l..+3 -> n = (4096-k)&4095: contiguous float4
        // at A = 4093-m0-4l, components REVERSED vs k. Dword-aligned only --
        // deliberate: keep the misalignment on the L1/L2-resident operand, not
        // on the weight HBM stream. Only it==0,lane==0 wraps (k=0 -> n=0).
        const int  A     = 4093 - m0 - (lane << 2);
        const bool wrap0 = (it == 0) && (lane == 0);

        float4 xg[4], xn[4];
#pragma unroll
        for (int u = 0; u < 4; ++u) {
            const float* xb = xci + (u << 19);   // b * CIN*LEN
            if (wrap0) { xg[u].x = xb[4093]; xg[u].y = xb[4094]; xg[u].z = xb[4095]; xg[u].w = xb[0]; }
            else        xg[u] = *(const float4*)(xb + A);
        }
#pragma unroll
        for (int bg = 0; bg < 4; ++bg) {
            if (bg < 3) {   // pipeline next batch group's x loads over the FMAs
#pragma unroll
                for (int u = 0; u < 4; ++u) {
                    const float* xb = xci + ((bg * 4 + 4 + u) << 19);
                    if (wrap0) { xn[u].x = xb[4093]; xn[u].y = xb[4094]; xn[u].z = xb[4095]; xn[u].w = xb[0]; }
                    else        xn[u] = *(const float4*)(xb + A);
                }
            }
#pragma unroll
            for (int u = 0; u < 4; ++u) {
                const int b = bg * 4 + u;
#pragma unroll
                for (int j = 0; j < 4; ++j) {
                    // reversed pairing: xv.w<->k=m0+4l (wr.x), etc.
                    acc[b][j] += xg[u].w * wcur[j].x;
                    acc[b][j] += xg[u].z * wcur[j].y;
                    acc[b][j] += xg[u].y * wcur[j].z;
                    acc[b][j] += xg[u].x * wcur[j].w;
                }
            }
            if (bg < 3) {
#pragma unroll
                for (int u = 0; u < 4; ++u) xg[u] = xn[u];
            }
        }
        if (it < 15) {
#pragma unroll
            for (int j = 0; j < 4; ++j) wcur[j] = wnxt[j];
        }
    }

    // epilogue: per-wave shuffle reduction over 64 lanes, one atomic per (b,o)
#pragma unroll
    for (int b = 0; b < BATCH; ++b) {
#pragma unroll
        for (int j = 0; j < 4; ++j) {
            float v = acc[b][j];
            v += __shfl_down(v, 32, 64);
            v += __shfl_down(v, 16, 64);
            v += __shfl_down(v, 8, 64);
            v += __shfl_down(v, 4, 64);
            v += __shfl_down(v, 2, 64);
            v += __shfl_down(v, 1, 64);
            if (lane == 0) atomicAdd(out + b * COUT_ + obase + j, v);
        }
    }
}

extern "C" void kernel_launch(void* const* d_in, const int* in_sizes, int n_in,
                              void* d_out, int out_size, void* d_ws, size_t ws_size,
                              hipStream_t stream) {
    const float* x    = (const float*)d_in[0];   // [16,128,4096]
    const float* wgt  = (const float*)d_in[1];   // [128,128,4096]
    const float* bias = (const float*)d_in[2];   // [128]
    float* out = (float*)d_out;                  // [16,128,1]
    (void)in_sizes; (void)n_in; (void)d_ws; (void)ws_size; (void)out_size;

    init_out_kernel<<<8, 256, 0, stream>>>(bias, out);
    conv_dot_kernel<<<1024, 256, 0, stream>>>(x, wgt, out);
}